// Round 14
// baseline (584.648 us; speedup 1.0000x reference)
//
#include <hip/hip_runtime.h>

#define FEAT 256
#define NNODES 2048

// ---------------- reductions (blockDim.x == 256 required) ----------------
__device__ __forceinline__ float blk_sum(float v) {
    __shared__ float tmp[4];
    #pragma unroll
    for (int o = 32; o > 0; o >>= 1) v += __shfl_down(v, o, 64);
    __syncthreads();
    if ((threadIdx.x & 63) == 0) tmp[threadIdx.x >> 6] = v;
    __syncthreads();
    return tmp[0] + tmp[1] + tmp[2] + tmp[3];
}

__device__ __forceinline__ float blk_max(float v) {
    __shared__ float tmp[4];
    #pragma unroll
    for (int o = 32; o > 0; o >>= 1) v = fmaxf(v, __shfl_down(v, o, 64));
    __syncthreads();
    if ((threadIdx.x & 63) == 0) tmp[threadIdx.x >> 6] = v;
    __syncthreads();
    return fmaxf(fmaxf(tmp[0], tmp[1]), fmaxf(tmp[2], tmp[3]));
}

__device__ __forceinline__ float wave_sum(float v) {
    #pragma unroll
    for (int o = 32; o > 0; o >>= 1) v += __shfl_down(v, o, 64);
    return v;
}

__global__ void fill_zero_k(float* p, int n) {
    for (int i = blockIdx.x * 256 + threadIdx.x; i < n; i += gridDim.x * 256) p[i] = 0.f;
}

// =================== bitmask adjacency + CSR build (level 0) ===================
__global__ void scatter_bit_k(const int* ei, unsigned* bm, int n, int ne) {
    int e = blockIdx.x * 256 + threadIdx.x;
    if (e < ne) {
        size_t idx = (size_t)ei[e] * n + ei[ne + e];
        atomicOr(&bm[idx >> 5], 1u << (idx & 31));
    }
}

__global__ void countbits_k(const unsigned* bm, int* cnt, int n) {
    int j = blockIdx.x, t = threadIdx.x;
    int words = n / 32;
    int c = (t < words) ? __popc(bm[(size_t)j * words + t]) : 0;
    #pragma unroll
    for (int o = 32; o > 0; o >>= 1) c += __shfl_down(c, o, 64);
    if (t == 0) cnt[j] = c + 1;   // +1 diag
}

__global__ void csr_scan_k(const int* cnt, int* rowptr, float* dinv, int n) {
    __shared__ int part[256];
    int t = threadIdx.x;
    int per = n / 256;
    int loc[8];
    int s = 0;
    for (int i = 0; i < per; i++) {
        loc[i] = s;
        int c = cnt[t * per + i];
        s += c;
        dinv[t * per + i] = rsqrtf((float)c);
    }
    part[t] = s;
    __syncthreads();
    for (int off = 1; off < 256; off <<= 1) {
        int v = (t >= off) ? part[t - off] : 0;
        __syncthreads();
        part[t] += v;
        __syncthreads();
    }
    int ex = (t == 0) ? 0 : part[t - 1];
    for (int i = 0; i < per; i++) rowptr[t * per + i] = ex + loc[i];
    if (t == 255) rowptr[n] = part[255];
}

__global__ void fillcsr_bits_k(const unsigned* bm, const int* rowptr, int* cols, int n) {
    int j = blockIdx.x, t = threadIdx.x;
    int words = n / 32;
    unsigned w = (t < words) ? bm[(size_t)j * words + t] : 0u;
    int c = __popc(w);
    int incl = c;
    #pragma unroll
    for (int o = 1; o < 64; o <<= 1) {
        int x = __shfl_up(incl, o, 64);
        if (t >= o) incl += x;
    }
    int base = rowptr[j] + 1 + (incl - c);
    if (t == 0) cols[rowptr[j]] = j;
    while (w) {
        int b = __ffs(w) - 1;
        cols[base++] = t * 32 + b;
        w &= w - 1;
    }
}

// =================== level-0 sparse kernels ===================
// + fused v[j] = dot(out_row_j, attw[256:512])
__global__ void sparse_gcn_k(const int* rowptr, const int* cols, const float* dinv,
                             const float* xW, const float* bias,
                             const float* attw, float* v, float* out) {
    int j = blockIdx.x, c = threadIdx.x;
    int r0 = rowptr[j], r1 = rowptr[j + 1];
    __shared__ int scol[256];
    __shared__ float sdv[256];
    float s = 0.f;
    for (int e0 = r0; e0 < r1; e0 += 256) {
        int m = min(256, r1 - e0);
        __syncthreads();
        if (c < m) { int ci = cols[e0 + c]; scol[c] = ci; sdv[c] = dinv[ci]; }
        __syncthreads();
        #pragma unroll 4
        for (int ii = 0; ii < m; ii++) s += sdv[ii] * xW[(size_t)scol[ii] * FEAT + c];
    }
    float o = fmaxf(dinv[j] * s + bias[c], 0.f);
    out[(size_t)j * FEAT + c] = o;
    float sv = blk_sum(o * attw[FEAT + c]);
    if (c == 0) v[j] = sv;
}

__global__ void sparse_mmax_k(const int* rowptr, const int* cols, const float* g, float* out) {
    int j = blockIdx.x, c = threadIdx.x;
    int r0 = rowptr[j], r1 = rowptr[j + 1];
    __shared__ int scol[256];
    float mv = -3.402823466e38f;
    for (int e0 = r0; e0 < r1; e0 += 256) {
        int m = min(256, r1 - e0);
        __syncthreads();
        if (c < m) scol[c] = cols[e0 + c];
        __syncthreads();
        #pragma unroll 4
        for (int ii = 0; ii < m; ii++) mv = fmaxf(mv, g[(size_t)scol[ii] * FEAT + c]);
    }
    out[(size_t)j * FEAT + c] = mv;
}

// merged score + xnew (+u, +abc): block j produces sval for row j and is its sole
// consumer in the xnew gather — body concatenation, __syncthreads() between
// (block-wide global visibility per __syncthreads semantics).
__global__ void sparse_sx_k(const int* rowptr, const int* cols, const float* xq,
                            const float* attw, const float* v, const float* attb,
                            const float* g,
                            const float* w1, const float* b1, const float* w2,
                            const float* w3, const float* b3,
                            float* a, float* bb, float* cf,
                            float* sval, float* xnew) {
    int j = blockIdx.x, c = threadIdx.x;
    int r0 = rowptr[j], r1 = rowptr[j + 1];
    // u[j] fused: coalesced row read + block reduce
    float uj = blk_sum(xq[(size_t)j * FEAT + c] * attw[c]) + attb[0];
    float mx = -3.402823466e38f;
    for (int e = r0 + c; e < r1; e += 256) {
        float r = v[cols[e]] + uj;
        r = (r >= 0.f) ? r : 0.2f * r;
        mx = fmaxf(mx, r);
    }
    mx = blk_max(mx);
    float sum = 0.f;
    for (int e = r0 + c; e < r1; e += 256) {
        float r = v[cols[e]] + uj;
        r = (r >= 0.f) ? r : 0.2f * r;
        sum += expf(r - mx);
    }
    sum = blk_sum(sum);
    for (int e = r0 + c; e < r1; e += 256) {
        float r = v[cols[e]] + uj;
        r = (r >= 0.f) ? r : 0.2f * r;
        sval[e] = expf(r - mx) / sum;
    }
    __syncthreads();   // sval writes visible block-wide
    // xnew gather
    __shared__ int scol[256];
    __shared__ float sv[256];
    float s = 0.f;
    for (int e0 = r0; e0 < r1; e0 += 256) {
        int m = min(256, r1 - e0);
        __syncthreads();
        if (c < m) { scol[c] = cols[e0 + c]; sv[c] = sval[e0 + c]; }
        __syncthreads();
        #pragma unroll 4
        for (int ii = 0; ii < m; ii++) s += sv[ii] * g[(size_t)scol[ii] * FEAT + c];
    }
    xnew[(size_t)j * FEAT + c] = s;
    float s1 = blk_sum(s * w1[c]);
    float s2 = blk_sum(s * w2[c]);
    float s3 = blk_sum(s * w3[c]);
    if (c == 0) { a[j] = s1 + b1[0]; bb[j] = s2; cf[j] = s3 + b3[0]; }
}

__global__ void sparse_fitness_k(const int* rowptr, const int* cols, const float* a,
                                 const float* bb, const float* cf, float* fit) {
    int j = blockIdx.x;
    int r0 = rowptr[j], r1 = rowptr[j + 1];
    float s = 0.f;
    for (int e = r0 + threadIdx.x; e < r1; e += 256) s += a[cols[e]];
    s = blk_sum(s);
    if (threadIdx.x == 0) {
        float z = s - (float)(r1 - r0) * bb[j] + cf[j];
        fit[j] = 1.f / (1.f + expf(-z));
    }
}

__global__ void sp_fill_k(const int* rowptr, const int* cols, const float* sval,
                          const int* perm, float* Sp, int kw) {
    int q = blockIdx.x;
    int row = perm[q];
    int r0 = rowptr[row], r1 = rowptr[row + 1];
    for (int e = r0 + threadIdx.x; e < r1; e += 256)
        Sp[(size_t)cols[e] * kw + q] = sval[e];
}

__global__ void z_k(const int* rowptr, const int* cols, const float* Sp, float* Z, int kw) {
    int j = blockIdx.x;
    int c4 = threadIdx.x * 4;
    int r0 = rowptr[j], r1 = rowptr[j + 1];
    __shared__ int scol[256];
    float4 acc = {0.f, 0.f, 0.f, 0.f};
    for (int e0 = r0; e0 < r1; e0 += 256) {
        int m = min(256, r1 - e0);
        __syncthreads();
        if (threadIdx.x < m) scol[threadIdx.x] = cols[e0 + threadIdx.x];
        __syncthreads();
        #pragma unroll 4
        for (int ii = 0; ii < m; ii++) {
            float4 s = *(const float4*)&Sp[(size_t)scol[ii] * kw + c4];
            acc.x += s.x; acc.y += s.y; acc.z += s.z; acc.w += s.w;
        }
    }
    *(float4*)&Z[(size_t)j * kw + c4] = acc;
}

// ac_k + fused row-sum -> dinv for the next level
__global__ void ac_k(const int* rowptr, const int* cols, const float* sval,
                     const int* perm, const float* Z, float* Aout, float* dinv, int kw) {
    int p = blockIdx.x;
    int row = perm[p];
    int c4 = threadIdx.x * 4;
    int r0 = rowptr[row], r1 = rowptr[row + 1];
    __shared__ int scol[256];
    __shared__ float sv[256];
    float4 acc = {0.f, 0.f, 0.f, 0.f};
    for (int e0 = r0; e0 < r1; e0 += 256) {
        int m = min(256, r1 - e0);
        __syncthreads();
        if (threadIdx.x < m) { scol[threadIdx.x] = cols[e0 + threadIdx.x]; sv[threadIdx.x] = sval[e0 + threadIdx.x]; }
        __syncthreads();
        #pragma unroll 4
        for (int ii = 0; ii < m; ii++) {
            float w = sv[ii];
            float4 z = *(const float4*)&Z[(size_t)scol[ii] * kw + c4];
            acc.x += w * z.x; acc.y += w * z.y; acc.z += w * z.z; acc.w += w * z.w;
        }
    }
    if (p >= c4 && p < c4 + 4) ((float*)&acc)[p - c4] = 0.f;
    *(float4*)&Aout[(size_t)p * kw + c4] = acc;
    __syncthreads();
    float ps = blk_sum(acc.x + acc.y + acc.z + acc.w);
    if (threadIdx.x == 0) dinv[p] = rsqrtf(ps + 1.0f);
}

// =================== 64x64-tile dense f32 GEMMs (full + split-K parts) ===================
#define LDT 68

__global__ __launch_bounds__(256) void gemm64_nn_k(const float* A, const float* B,
                                                   const float* bias, float* C,
                                                   int M, int N, int K) {
    __shared__ float As[16][LDT];
    __shared__ float Bs[16][LDT];
    int t = threadIdx.x;
    int tx = t & 15, ty = t >> 4;
    int ar = t >> 2, akq = t & 3;
    int bkr = t >> 4, bcq = t & 15;
    const float* Ab = A + (size_t)(blockIdx.y * 64 + ar) * K + akq * 4;
    const float* Bb = B + (size_t)bkr * N + blockIdx.x * 64 + bcq * 4;
    float acc[4][4] = {};
    for (int k0 = 0; k0 < K; k0 += 16) {
        float4 av = *(const float4*)(Ab + k0);
        float4 bv = *(const float4*)(Bb + (size_t)k0 * N);
        As[akq * 4 + 0][ar] = av.x; As[akq * 4 + 1][ar] = av.y;
        As[akq * 4 + 2][ar] = av.z; As[akq * 4 + 3][ar] = av.w;
        *(float4*)&Bs[bkr][bcq * 4] = bv;
        __syncthreads();
        #pragma unroll
        for (int kk = 0; kk < 16; kk++) {
            float4 a = *(const float4*)&As[kk][ty * 4];
            float4 b = *(const float4*)&Bs[kk][tx * 4];
            acc[0][0] += a.x * b.x; acc[0][1] += a.x * b.y; acc[0][2] += a.x * b.z; acc[0][3] += a.x * b.w;
            acc[1][0] += a.y * b.x; acc[1][1] += a.y * b.y; acc[1][2] += a.y * b.z; acc[1][3] += a.y * b.w;
            acc[2][0] += a.z * b.x; acc[2][1] += a.z * b.y; acc[2][2] += a.z * b.z; acc[2][3] += a.z * b.w;
            acc[3][0] += a.w * b.x; acc[3][1] += a.w * b.y; acc[3][2] += a.w * b.z; acc[3][3] += a.w * b.w;
        }
        __syncthreads();
    }
    int cb = blockIdx.x * 64 + tx * 4;
    float4 bv = {0.f, 0.f, 0.f, 0.f};
    if (bias) bv = *(const float4*)&bias[cb];
    #pragma unroll
    for (int i = 0; i < 4; i++) {
        int row = blockIdx.y * 64 + ty * 4 + i;
        float4 o = {acc[i][0] + bv.x, acc[i][1] + bv.y, acc[i][2] + bv.z, acc[i][3] + bv.w};
        *(float4*)&C[(size_t)row * N + cb] = o;
    }
}

__global__ __launch_bounds__(256) void gemm64_nn_part_k(const float* A, const float* B,
                                                        float* part, int M, int N, int K,
                                                        int kch) {
    __shared__ float As[16][LDT];
    __shared__ float Bs[16][LDT];
    int t = threadIdx.x;
    int tx = t & 15, ty = t >> 4;
    int ar = t >> 2, akq = t & 3;
    int bkr = t >> 4, bcq = t & 15;
    int ks = blockIdx.z * kch;
    const float* Ab = A + (size_t)(blockIdx.y * 64 + ar) * K + akq * 4;
    const float* Bb = B + (size_t)bkr * N + blockIdx.x * 64 + bcq * 4;
    float acc[4][4] = {};
    for (int k0 = ks; k0 < ks + kch; k0 += 16) {
        float4 av = *(const float4*)(Ab + k0);
        float4 bv = *(const float4*)(Bb + (size_t)k0 * N);
        As[akq * 4 + 0][ar] = av.x; As[akq * 4 + 1][ar] = av.y;
        As[akq * 4 + 2][ar] = av.z; As[akq * 4 + 3][ar] = av.w;
        *(float4*)&Bs[bkr][bcq * 4] = bv;
        __syncthreads();
        #pragma unroll
        for (int kk = 0; kk < 16; kk++) {
            float4 a = *(const float4*)&As[kk][ty * 4];
            float4 b = *(const float4*)&Bs[kk][tx * 4];
            acc[0][0] += a.x * b.x; acc[0][1] += a.x * b.y; acc[0][2] += a.x * b.z; acc[0][3] += a.x * b.w;
            acc[1][0] += a.y * b.x; acc[1][1] += a.y * b.y; acc[1][2] += a.y * b.z; acc[1][3] += a.y * b.w;
            acc[2][0] += a.z * b.x; acc[2][1] += a.z * b.y; acc[2][2] += a.z * b.z; acc[2][3] += a.z * b.w;
            acc[3][0] += a.w * b.x; acc[3][1] += a.w * b.y; acc[3][2] += a.w * b.z; acc[3][3] += a.w * b.w;
        }
        __syncthreads();
    }
    int cb = blockIdx.x * 64 + tx * 4;
    float* out = part + (size_t)blockIdx.z * M * N;
    #pragma unroll
    for (int i = 0; i < 4; i++) {
        int row = blockIdx.y * 64 + ty * 4 + i;
        float4 o = {acc[i][0], acc[i][1], acc[i][2], acc[i][3]};
        *(float4*)&out[(size_t)row * N + cb] = o;
    }
}

__global__ __launch_bounds__(256) void gcn64_part_k(const float* A, const float* dinv,
                                                    const float* xW, float* part,
                                                    int n, int kch) {
    __shared__ float As[16][LDT];
    __shared__ float Bs[16][LDT];
    int t = threadIdx.x;
    int tx = t & 15, ty = t >> 4;
    int ar = t >> 2, akq = t & 3;
    int bkr = t >> 4, bcq = t & 15;
    int arow = blockIdx.y * 64 + ar;
    int ks = blockIdx.z * kch;
    const float* Ab = A + (size_t)arow * n + akq * 4;
    const float* Bb = xW + (size_t)bkr * FEAT + blockIdx.x * 64 + bcq * 4;
    float acc[4][4] = {};
    float dj = dinv[arow];
    for (int k0 = ks; k0 < ks + kch; k0 += 16) {
        int ibase = k0 + akq * 4;
        float4 av = *(const float4*)(Ab + k0);
        float4 dv = *(const float4*)&dinv[ibase];
        As[akq * 4 + 0][ar] = (ibase + 0 == arow) ? dj : av.x * dv.x;
        As[akq * 4 + 1][ar] = (ibase + 1 == arow) ? dj : av.y * dv.y;
        As[akq * 4 + 2][ar] = (ibase + 2 == arow) ? dj : av.z * dv.z;
        As[akq * 4 + 3][ar] = (ibase + 3 == arow) ? dj : av.w * dv.w;
        float4 bv = *(const float4*)(Bb + (size_t)k0 * FEAT);
        *(float4*)&Bs[bkr][bcq * 4] = bv;
        __syncthreads();
        #pragma unroll
        for (int kk = 0; kk < 16; kk++) {
            float4 a = *(const float4*)&As[kk][ty * 4];
            float4 b = *(const float4*)&Bs[kk][tx * 4];
            acc[0][0] += a.x * b.x; acc[0][1] += a.x * b.y; acc[0][2] += a.x * b.z; acc[0][3] += a.x * b.w;
            acc[1][0] += a.y * b.x; acc[1][1] += a.y * b.y; acc[1][2] += a.y * b.z; acc[1][3] += a.y * b.w;
            acc[2][0] += a.z * b.x; acc[2][1] += a.z * b.y; acc[2][2] += a.z * b.z; acc[2][3] += a.z * b.w;
            acc[3][0] += a.w * b.x; acc[3][1] += a.w * b.y; acc[3][2] += a.w * b.z; acc[3][3] += a.w * b.w;
        }
        __syncthreads();
    }
    int cb = blockIdx.x * 64 + tx * 4;
    float* out = part + (size_t)blockIdx.z * n * FEAT;
    #pragma unroll
    for (int i = 0; i < 4; i++) {
        int row = blockIdx.y * 64 + ty * 4 + i;
        float4 o = {acc[i][0], acc[i][1], acc[i][2], acc[i][3]};
        *(float4*)&out[(size_t)row * FEAT + cb] = o;
    }
}

__global__ __launch_bounds__(256) void mmax64_part_k(const float* A, const float* g,
                                                     float* part, int n, int kch) {
    __shared__ float As[16][LDT];
    __shared__ float Bs[16][LDT];
    int t = threadIdx.x;
    int tx = t & 15, ty = t >> 4;
    int ar = t >> 2, akq = t & 3;
    int bkr = t >> 4, bcq = t & 15;
    int arow = blockIdx.y * 64 + ar;
    int ks = blockIdx.z * kch;
    const float* Ab = A + (size_t)arow * n + akq * 4;
    const float* Bb = g + (size_t)bkr * FEAT + blockIdx.x * 64 + bcq * 4;
    const float NEG = -3.402823466e38f;
    float acc[4][4] = {{NEG, NEG, NEG, NEG}, {NEG, NEG, NEG, NEG},
                       {NEG, NEG, NEG, NEG}, {NEG, NEG, NEG, NEG}};
    for (int k0 = ks; k0 < ks + kch; k0 += 16) {
        int ibase = k0 + akq * 4;
        float4 av = *(const float4*)(Ab + k0);
        As[akq * 4 + 0][ar] = (av.x != 0.f || ibase + 0 == arow) ? 0.f : NEG;
        As[akq * 4 + 1][ar] = (av.y != 0.f || ibase + 1 == arow) ? 0.f : NEG;
        As[akq * 4 + 2][ar] = (av.z != 0.f || ibase + 2 == arow) ? 0.f : NEG;
        As[akq * 4 + 3][ar] = (av.w != 0.f || ibase + 3 == arow) ? 0.f : NEG;
        float4 bv = *(const float4*)(Bb + (size_t)k0 * FEAT);
        *(float4*)&Bs[bkr][bcq * 4] = bv;
        __syncthreads();
        #pragma unroll
        for (int kk = 0; kk < 16; kk++) {
            float4 a = *(const float4*)&As[kk][ty * 4];
            float4 b = *(const float4*)&Bs[kk][tx * 4];
            acc[0][0] = fmaxf(acc[0][0], b.x + a.x); acc[0][1] = fmaxf(acc[0][1], b.y + a.x);
            acc[0][2] = fmaxf(acc[0][2], b.z + a.x); acc[0][3] = fmaxf(acc[0][3], b.w + a.x);
            acc[1][0] = fmaxf(acc[1][0], b.x + a.y); acc[1][1] = fmaxf(acc[1][1], b.y + a.y);
            acc[1][2] = fmaxf(acc[1][2], b.z + a.y); acc[1][3] = fmaxf(acc[1][3], b.w + a.y);
            acc[2][0] = fmaxf(acc[2][0], b.x + a.z); acc[2][1] = fmaxf(acc[2][1], b.y + a.z);
            acc[2][2] = fmaxf(acc[2][2], b.z + a.z); acc[2][3] = fmaxf(acc[2][3], b.w + a.z);
            acc[3][0] = fmaxf(acc[3][0], b.x + a.w); acc[3][1] = fmaxf(acc[3][1], b.y + a.w);
            acc[3][2] = fmaxf(acc[3][2], b.z + a.w); acc[3][3] = fmaxf(acc[3][3], b.w + a.w);
        }
        __syncthreads();
    }
    int cb = blockIdx.x * 64 + tx * 4;
    float* out = part + (size_t)blockIdx.z * n * FEAT;
    #pragma unroll
    for (int i = 0; i < 4; i++) {
        int row = blockIdx.y * 64 + ty * 4 + i;
        float4 o = {acc[i][0], acc[i][1], acc[i][2], acc[i][3]};
        *(float4*)&out[(size_t)row * FEAT + cb] = o;
    }
}

// A rows read through perm: A_logical[row] = A[perm[row]]
__global__ __launch_bounds__(256) void gemm64_maskBp_part_k(const float* A, const int* perm,
                                                            const float* Adj, float* part,
                                                            int M, int N, int K, int kch) {
    __shared__ float As[16][LDT];
    __shared__ float Bs[16][LDT];
    int t = threadIdx.x;
    int tx = t & 15, ty = t >> 4;
    int ar = t >> 2, akq = t & 3;
    int bkr = t >> 4, bcq = t & 15;
    int ks = blockIdx.z * kch;
    const float* Ab = A + (size_t)perm[blockIdx.y * 64 + ar] * K + akq * 4;
    int cbase = blockIdx.x * 64 + bcq * 4;
    float acc[4][4] = {};
    for (int k0 = ks; k0 < ks + kch; k0 += 16) {
        float4 av = *(const float4*)(Ab + k0);
        int brow = k0 + bkr;
        float4 adj = *(const float4*)&Adj[(size_t)brow * N + cbase];
        As[akq * 4 + 0][ar] = av.x; As[akq * 4 + 1][ar] = av.y;
        As[akq * 4 + 2][ar] = av.z; As[akq * 4 + 3][ar] = av.w;
        Bs[bkr][bcq * 4 + 0] = (adj.x != 0.f || brow == cbase + 0) ? 1.f : 0.f;
        Bs[bkr][bcq * 4 + 1] = (adj.y != 0.f || brow == cbase + 1) ? 1.f : 0.f;
        Bs[bkr][bcq * 4 + 2] = (adj.z != 0.f || brow == cbase + 2) ? 1.f : 0.f;
        Bs[bkr][bcq * 4 + 3] = (adj.w != 0.f || brow == cbase + 3) ? 1.f : 0.f;
        __syncthreads();
        #pragma unroll
        for (int kk = 0; kk < 16; kk++) {
            float4 a = *(const float4*)&As[kk][ty * 4];
            float4 b = *(const float4*)&Bs[kk][tx * 4];
            acc[0][0] += a.x * b.x; acc[0][1] += a.x * b.y; acc[0][2] += a.x * b.z; acc[0][3] += a.x * b.w;
            acc[1][0] += a.y * b.x; acc[1][1] += a.y * b.y; acc[1][2] += a.y * b.z; acc[1][3] += a.y * b.w;
            acc[2][0] += a.z * b.x; acc[2][1] += a.z * b.y; acc[2][2] += a.z * b.z; acc[2][3] += a.z * b.w;
            acc[3][0] += a.w * b.x; acc[3][1] += a.w * b.y; acc[3][2] += a.w * b.z; acc[3][3] += a.w * b.w;
        }
        __syncthreads();
    }
    int cb = blockIdx.x * 64 + tx * 4;
    float* out = part + (size_t)blockIdx.z * M * N;
    #pragma unroll
    for (int i = 0; i < 4; i++) {
        int row = blockIdx.y * 64 + ty * 4 + i;
        float4 o = {acc[i][0], acc[i][1], acc[i][2], acc[i][3]};
        *(float4*)&out[(size_t)row * N + cb] = o;
    }
}

// B rows read through perm: B_logical[col] = B[perm[col]]
__global__ __launch_bounds__(256) void gemm64_ntp_part_k(const float* A, const float* B,
                                                         const int* perm, float* part,
                                                         int M, int N, int K, int kch) {
    __shared__ float As[16][LDT];
    __shared__ float Bs[16][LDT];
    int t = threadIdx.x;
    int tx = t & 15, ty = t >> 4;
    int ar = t >> 2, akq = t & 3;
    int ks = blockIdx.z * kch;
    const float* Ab = A + (size_t)(blockIdx.y * 64 + ar) * K + akq * 4;
    const float* Bb = B + (size_t)perm[blockIdx.x * 64 + ar] * K + akq * 4;
    float acc[4][4] = {};
    for (int k0 = ks; k0 < ks + kch; k0 += 16) {
        float4 av = *(const float4*)(Ab + k0);
        float4 bv = *(const float4*)(Bb + k0);
        As[akq * 4 + 0][ar] = av.x; As[akq * 4 + 1][ar] = av.y;
        As[akq * 4 + 2][ar] = av.z; As[akq * 4 + 3][ar] = av.w;
        Bs[akq * 4 + 0][ar] = bv.x; Bs[akq * 4 + 1][ar] = bv.y;
        Bs[akq * 4 + 2][ar] = bv.z; Bs[akq * 4 + 3][ar] = bv.w;
        __syncthreads();
        #pragma unroll
        for (int kk = 0; kk < 16; kk++) {
            float4 a = *(const float4*)&As[kk][ty * 4];
            float4 b = *(const float4*)&Bs[kk][tx * 4];
            acc[0][0] += a.x * b.x; acc[0][1] += a.x * b.y; acc[0][2] += a.x * b.z; acc[0][3] += a.x * b.w;
            acc[1][0] += a.y * b.x; acc[1][1] += a.y * b.y; acc[1][2] += a.y * b.z; acc[1][3] += a.y * b.w;
            acc[2][0] += a.z * b.x; acc[2][1] += a.z * b.y; acc[2][2] += a.z * b.z; acc[2][3] += a.z * b.w;
            acc[3][0] += a.w * b.x; acc[3][1] += a.w * b.y; acc[3][2] += a.w * b.z; acc[3][3] += a.w * b.w;
        }
        __syncthreads();
    }
    int cb = blockIdx.x * 64 + tx * 4;
    float* out = part + (size_t)blockIdx.z * M * N;
    #pragma unroll
    for (int i = 0; i < 4; i++) {
        int row = blockIdx.y * 64 + ty * 4 + i;
        float4 o = {acc[i][0], acc[i][1], acc[i][2], acc[i][3]};
        *(float4*)&out[(size_t)row * N + cb] = o;
    }
}

// ---------------- comb variants ----------------
__global__ void comb_k(const float* part, float* out, const float* bias,
                       int MN, int N, int S, int mode) {
    int i4 = (blockIdx.x * 256 + threadIdx.x) * 4;
    if (i4 >= MN) return;
    float4 v;
    if (mode == 1) {
        v = *(const float4*)&part[i4];
        for (int s = 1; s < S; s++) {
            float4 p = *(const float4*)&part[(size_t)s * MN + i4];
            v.x = fmaxf(v.x, p.x); v.y = fmaxf(v.y, p.y);
            v.z = fmaxf(v.z, p.z); v.w = fmaxf(v.w, p.w);
        }
    } else {
        v = make_float4(0.f, 0.f, 0.f, 0.f);
        for (int s = 0; s < S; s++) {
            float4 p = *(const float4*)&part[(size_t)s * MN + i4];
            v.x += p.x; v.y += p.y; v.z += p.z; v.w += p.w;
        }
        if (bias) {
            int col = i4 % N;
            float4 bv = *(const float4*)&bias[col];
            v.x += bv.x; v.y += bv.y; v.z += bv.z; v.w += bv.w;
        }
    }
    *(float4*)&out[i4] = v;
}

__global__ void comb_relu_v_k(const float* part, float* out, const float* bias,
                              const float* dinv, const float* attw, float* v,
                              int MN, int S) {
    int t = threadIdx.x;
    int i4 = (blockIdx.x * 256 + t) * 4;
    float4 s = make_float4(0.f, 0.f, 0.f, 0.f);
    for (int ss = 0; ss < S; ss++) {
        float4 p = *(const float4*)&part[(size_t)ss * MN + i4];
        s.x += p.x; s.y += p.y; s.z += p.z; s.w += p.w;
    }
    int row = i4 >> 8;
    int col = i4 & 255;
    float dj = dinv[row];
    float4 bv = *(const float4*)&bias[col];
    float4 o = {fmaxf(dj * s.x + bv.x, 0.f), fmaxf(dj * s.y + bv.y, 0.f),
                fmaxf(dj * s.z + bv.z, 0.f), fmaxf(dj * s.w + bv.w, 0.f)};
    *(float4*)&out[i4] = o;
    float4 aw = *(const float4*)&attw[256 + col];
    float pv = wave_sum(o.x * aw.x + o.y * aw.y + o.z * aw.z + o.w * aw.w);
    if ((t & 63) == 0) v[row] = pv;
}

__global__ void comb_sum_u_k(const float* part, float* out, const float* bias,
                             const float* attw, float* u, int MN, int S) {
    int t = threadIdx.x;
    int i4 = (blockIdx.x * 256 + t) * 4;
    float4 s = make_float4(0.f, 0.f, 0.f, 0.f);
    for (int ss = 0; ss < S; ss++) {
        float4 p = *(const float4*)&part[(size_t)ss * MN + i4];
        s.x += p.x; s.y += p.y; s.z += p.z; s.w += p.w;
    }
    int row = i4 >> 8;
    int col = i4 & 255;
    float4 bv = *(const float4*)&bias[col];
    float4 o = {s.x + bv.x, s.y + bv.y, s.z + bv.z, s.w + bv.w};
    *(float4*)&out[i4] = o;
    float4 aw = *(const float4*)&attw[col];
    float pu = wave_sum(o.x * aw.x + o.y * aw.y + o.z * aw.z + o.w * aw.w);
    if ((t & 63) == 0) u[row] = pu;
}

__global__ void comb_sum_abc_k(const float* part, float* out,
                               const float* w1, const float* b1, const float* w2,
                               const float* w3, const float* b3,
                               float* a, float* bb, float* cf, int MN, int S) {
    int t = threadIdx.x;
    int i4 = (blockIdx.x * 256 + t) * 4;
    float4 s = make_float4(0.f, 0.f, 0.f, 0.f);
    for (int ss = 0; ss < S; ss++) {
        float4 p = *(const float4*)&part[(size_t)ss * MN + i4];
        s.x += p.x; s.y += p.y; s.z += p.z; s.w += p.w;
    }
    *(float4*)&out[i4] = s;
    int row = i4 >> 8;
    int col = i4 & 255;
    float4 v1 = *(const float4*)&w1[col];
    float4 v2 = *(const float4*)&w2[col];
    float4 v3 = *(const float4*)&w3[col];
    float p1 = wave_sum(s.x * v1.x + s.y * v1.y + s.z * v1.z + s.w * v1.w);
    float p2 = wave_sum(s.x * v2.x + s.y * v2.y + s.z * v2.z + s.w * v2.w);
    float p3 = wave_sum(s.x * v3.x + s.y * v3.y + s.z * v3.z + s.w * v3.w);
    if ((t & 63) == 0) {
        a[row] = p1 + b1[0];
        bb[row] = p2;
        cf[row] = p3 + b3[0];
    }
}

__global__ void comb_diag_deg_k(const float* part, float* out, float* dinv,
                                int MN, int N, int S) {
    int t = threadIdx.x;
    int i4 = (blockIdx.x * 256 + t) * 4;
    float4 s = make_float4(0.f, 0.f, 0.f, 0.f);
    for (int ss = 0; ss < S; ss++) {
        float4 p = *(const float4*)&part[(size_t)ss * MN + i4];
        s.x += p.x; s.y += p.y; s.z += p.z; s.w += p.w;
    }
    int row = i4 / N, col = i4 % N;
    if (row >= col && row < col + 4) ((float*)&s)[row - col] = 0.f;
    *(float4*)&out[i4] = s;
    float ps = wave_sum(s.x + s.y + s.z + s.w);
    __shared__ float rsum[4];
    if ((t & 63) == 0) rsum[t >> 6] = ps;
    __syncthreads();
    if (t == 0) dinv[row] = rsqrtf(rsum[0] + rsum[1] + 1.0f);
    if (t == 128) dinv[row] = rsqrtf(rsum[2] + rsum[3] + 1.0f);
}

// =================== per-row kernels ===================
// single-pass score with compile-time PER (register arrays; no spill)
template<int PER>
__global__ void score_tk(const float* A, const float* u, const float* v, const float* attb,
                         float* T, int n) {
    int j = blockIdx.x, t = threadIdx.x;
    float uj = u[j] + attb[0];
    float rv[PER];
    int mk[PER];
    float mxl = -3.402823466e38f;
    #pragma unroll
    for (int ii = 0; ii < PER; ii++) {
        int i = ii * 256 + t;
        bool m = (i == j) || (A[(size_t)j * n + i] != 0.f);
        float r = v[i] + uj;
        r = (r >= 0.f) ? r : 0.2f * r;
        rv[ii] = r;
        mk[ii] = m;
        mxl = fmaxf(mxl, m ? r : -3.402823466e38f);
    }
    float mx = blk_max(mxl);
    float ev[PER];
    float sl = 0.f;
    #pragma unroll
    for (int ii = 0; ii < PER; ii++) {
        ev[ii] = mk[ii] ? expf(rv[ii] - mx) : 0.f;
        sl += ev[ii];
    }
    float sum = blk_sum(sl);
    #pragma unroll
    for (int ii = 0; ii < PER; ii++) {
        int i = ii * 256 + t;
        T[(size_t)j * n + i] = mk[ii] ? (ev[ii] / sum) : 0.f;
    }
}

__global__ void fitness_k(const float* A, const float* a, const float* bb, const float* cf,
                          float* fit, int n) {
    int j = blockIdx.x;
    float s = 0.f, d = 0.f;
    for (int i = threadIdx.x; i < n; i += 256) {
        bool msk = (i == j) || (A[(size_t)j * n + i] != 0.f);
        float av = a[i];
        s += msk ? av : 0.f;
        d += msk ? 1.f : 0.f;
    }
    s = blk_sum(s);
    d = blk_sum(d);
    if (threadIdx.x == 0) {
        float z = s - d * bb[j] + cf[j];
        fit[j] = 1.f / (1.f + expf(-z));
    }
}

__global__ void topk_k(const float* fitv, int n, int k, int* perm, float* fvals) {
    __shared__ float sf[2048];
    __shared__ int si[2048];
    for (int i = threadIdx.x; i < n; i += blockDim.x) { sf[i] = fitv[i]; si[i] = i; }
    __syncthreads();
    for (int sz = 2; sz <= n; sz <<= 1) {
        for (int st = sz >> 1; st > 0; st >>= 1) {
            for (int i = threadIdx.x; i < n; i += blockDim.x) {
                int jj = i ^ st;
                if (jj > i) {
                    bool up = ((i & sz) == 0);
                    float fi_ = sf[i], fj_ = sf[jj];
                    int ii_ = si[i], ij_ = si[jj];
                    bool before = (fi_ > fj_) || (fi_ == fj_ && ii_ < ij_);
                    if (up ? !before : before) {
                        sf[i] = fj_; sf[jj] = fi_;
                        si[i] = ij_; si[jj] = ii_;
                    }
                }
            }
            __syncthreads();
        }
    }
    for (int i = threadIdx.x; i < k; i += blockDim.x) { perm[i] = si[i]; fvals[i] = sf[i]; }
}

__global__ void gather_x_k(const float* xnew, const int* perm, const float* fvals, float* xout) {
    int p = blockIdx.x, c = threadIdx.x;
    xout[(size_t)p * FEAT + c] = xnew[(size_t)perm[p] * FEAT + c] * fvals[p];
}

__global__ void readout_part_k(const float* h, float* psum, float* pmax, int k, int lvl_off) {
    int b = blockIdx.x, c = threadIdx.x;
    int r0 = b * 64, r1 = min(r0 + 64, k);
    float s = 0.f, m = -3.402823466e38f;
    for (int j = r0; j < r1; j++) {
        float x = h[(size_t)j * FEAT + c];
        s += x;
        m = fmaxf(m, x);
    }
    psum[lvl_off + b * FEAT + c] = s;
    pmax[lvl_off + b * FEAT + c] = m;
}

__global__ void final_k(const float* psum, const float* pmax,
                        const float* l1W, const float* l1b,
                        const float* l2W, const float* l2b, float* out, int osz) {
    __shared__ float ro[512];
    __shared__ float hid[256];
    __shared__ float logits[10];
    int c = threadIdx.x;
    const int nb[3] = {16, 8, 4};
    const float kl[3] = {1024.f, 512.f, 256.f};
    float st = 0.f, mt = 0.f;
    for (int l = 0; l < 3; l++) {
        float s = 0.f, m = -3.402823466e38f;
        int off = l * 16 * FEAT;
        for (int b = 0; b < nb[l]; b++) {
            s += psum[off + b * FEAT + c];
            m = fmaxf(m, pmax[off + b * FEAT + c]);
        }
        st += s / kl[l];
        mt += m;
    }
    ro[c] = st;
    ro[FEAT + c] = mt;
    __syncthreads();
    float s = l1b[c];
    for (int kk = 0; kk < 512; kk++) s += ro[kk] * l1W[(size_t)kk * 256 + c];
    hid[c] = fmaxf(s, 0.f);
    __syncthreads();
    if (c < 10) {
        float t = l2b[c];
        for (int kk = 0; kk < 256; kk++) t += hid[kk] * l2W[(size_t)kk * 10 + c];
        logits[c] = t;
    }
    __syncthreads();
    if (c == 0) {
        float mx = -3.402823466e38f;
        for (int i = 0; i < 10; i++) mx = fmaxf(mx, logits[i]);
        float se = 0.f;
        for (int i = 0; i < 10; i++) se += expf(logits[i] - mx);
        float lse = mx + logf(se);
        for (int i = 0; i < osz && i < 10; i++) out[i] = logits[i] - lse;
    }
}

// ---------------- host ----------------
extern "C" void kernel_launch(void* const* d_in, const int* in_sizes, int n_in,
                              void* d_out, int out_size, void* d_ws, size_t ws_size,
                              hipStream_t stream) {
    (void)n_in; (void)ws_size;
    float* base = (float*)d_ws;
    size_t off = 0;
    auto alloc = [&](size_t cnt) { float* p = base + off; off += cnt; return p; };

    float* A_a   = alloc((size_t)1024 * 1024);
    float* A_b   = alloc((size_t)1024 * 1024);
    float* Tm    = alloc((size_t)1024 * 1024);
    float* Yb    = alloc((size_t)512 * 1024);
    float* Sp    = alloc((size_t)2048 * 1024);
    float* Zb    = alloc((size_t)2048 * 1024);
    float* pbuf  = alloc((size_t)8 * 1024 * 256);
    float* xW    = alloc((size_t)2048 * 256);
    float* gb    = alloc((size_t)2048 * 256);
    float* mmb   = alloc((size_t)2048 * 256);
    float* xq    = alloc((size_t)2048 * 256);
    float* xnew  = alloc((size_t)2048 * 256);
    float* xout  = alloc((size_t)1024 * 256);
    float* dinv  = alloc(2048);
    float* ub    = alloc(2048);
    float* vb    = alloc(2048);
    float* aar   = alloc(2048);
    float* bbr   = alloc(2048);
    float* cfr   = alloc(2048);
    float* fit   = alloc(2048);
    float* fvals = alloc(2048);
    int*   perm  = (int*)alloc(2048);
    float* psum  = alloc(3 * 16 * FEAT);
    float* pmax  = alloc(3 * 16 * FEAT);
    unsigned* bm = (unsigned*)alloc(NNODES * NNODES / 32);
    int*   rowcnt = (int*)alloc(2048);
    int*   rowptr = (int*)alloc(2052);
    int*   csr_cols = (int*)alloc(80000);
    float* sval     = alloc(80000);

    const float* x     = (const float*)d_in[0];
    const int*   ei    = (const int*)d_in[1];
    const float* cW1   = (const float*)d_in[2];
    const float* cb1   = (const float*)d_in[3];
    const float* cW2   = (const float*)d_in[4];
    const float* cb2   = (const float*)d_in[5];
    const float* clinW = (const float*)d_in[6];
    const float* clinb = (const float*)d_in[7];
    const float* cattw = (const float*)d_in[8];
    const float* cattb = (const float*)d_in[9];
    const float* cle1W = (const float*)d_in[10];
    const float* cle1b = (const float*)d_in[11];
    const float* cle2W = (const float*)d_in[12];
    const float* cle3W = (const float*)d_in[13];
    const float* cle3b = (const float*)d_in[14];
    const float* cl1W  = (const float*)d_in[15];
    const float* cl1b  = (const float*)d_in[16];
    const float* cl2W  = (const float*)d_in[17];
    const float* cl2b  = (const float*)d_in[18];

    // ================= level 0: bitmask CSR + sparse path =================
    {
        int n = NNODES, k = n >> 1;
        fill_zero_k<<<512, 256, 0, stream>>>((float*)bm, n * n / 32);
        scatter_bit_k<<<(in_sizes[1] / 2 + 255) / 256, 256, 0, stream>>>(
            ei, bm, n, in_sizes[1] / 2);
        countbits_k<<<n, 64, 0, stream>>>(bm, rowcnt, n);
        csr_scan_k<<<1, 256, 0, stream>>>(rowcnt, rowptr, dinv, n);
        fillcsr_bits_k<<<n, 64, 0, stream>>>(bm, rowptr, csr_cols, n);

        gemm64_nn_k<<<dim3(FEAT / 64, n / 64), 256, 0, stream>>>(
            x, cW1, nullptr, xW, n, FEAT, 128);
        sparse_gcn_k<<<n, 256, 0, stream>>>(rowptr, csr_cols, dinv, xW, cb1,
                                            cattw, vb, gb);
        sparse_mmax_k<<<n, 256, 0, stream>>>(rowptr, csr_cols, gb, mmb);
        gemm64_nn_k<<<dim3(FEAT / 64, n / 64), 256, 0, stream>>>(
            mmb, clinW, clinb, xq, n, FEAT, FEAT);
        sparse_sx_k<<<n, 256, 0, stream>>>(rowptr, csr_cols, xq, cattw, vb, cattb, gb,
                                           cle1W, cle1b, cle2W, cle3W, cle3b,
                                           aar, bbr, cfr, sval, xnew);
        sparse_fitness_k<<<n, 256, 0, stream>>>(rowptr, csr_cols, aar, bbr, cfr, fit);
        topk_k<<<1, 1024, 0, stream>>>(fit, n, k, perm, fvals);
        gather_x_k<<<k, 256, 0, stream>>>(xnew, perm, fvals, xout);
        readout_part_k<<<k / 64, 256, 0, stream>>>(xout, psum, pmax, k, 0);

        fill_zero_k<<<2048, 256, 0, stream>>>(Sp, n * k);
        sp_fill_k<<<k, 256, 0, stream>>>(rowptr, csr_cols, sval, perm, Sp, k);
        z_k<<<n, 256, 0, stream>>>(rowptr, csr_cols, Sp, Zb, k);
        ac_k<<<k, 256, 0, stream>>>(rowptr, csr_cols, sval, perm, Zb, A_b, dinv, k);
    }

    // ================= levels 1-2: dense split-K path (fused combs) =================
    const float* Acur = A_b;
    float* Anext = A_a;
    const float* hcur = xout;
    int n = 1024;
    for (int lvl = 1; lvl < 3; lvl++) {
        int k = n >> 1;
        int S  = 8;
        int Sw = (n == 1024) ? 4 : 8;
        int nMN = n * FEAT;
        int cgrid = nMN / 4 / 256;

        gemm64_nn_part_k<<<dim3(FEAT / 64, n / 64, Sw), 256, 0, stream>>>(
            hcur, cW2, pbuf, n, FEAT, FEAT, FEAT / Sw);
        comb_k<<<cgrid, 256, 0, stream>>>(pbuf, xW, nullptr, nMN, FEAT, Sw, 0);
        gcn64_part_k<<<dim3(FEAT / 64, n / 64, S), 256, 0, stream>>>(
            Acur, dinv, xW, pbuf, n, n / S);
        comb_relu_v_k<<<cgrid, 256, 0, stream>>>(pbuf, gb, cb2, dinv, cattw, vb, nMN, S);
        mmax64_part_k<<<dim3(FEAT / 64, n / 64, S), 256, 0, stream>>>(
            Acur, gb, pbuf, n, n / S);
        comb_k<<<cgrid, 256, 0, stream>>>(pbuf, mmb, nullptr, nMN, FEAT, S, 1);
        gemm64_nn_part_k<<<dim3(FEAT / 64, n / 64, Sw), 256, 0, stream>>>(
            mmb, clinW, pbuf, n, FEAT, FEAT, FEAT / Sw);
        comb_sum_u_k<<<cgrid, 256, 0, stream>>>(pbuf, xq, clinb, cattw, ub, nMN, Sw);
        if (n == 1024)
            score_tk<4><<<n, 256, 0, stream>>>(Acur, ub, vb, cattb, Tm, n);
        else
            score_tk<2><<<n, 256, 0, stream>>>(Acur, ub, vb, cattb, Tm, n);
        gemm64_nn_part_k<<<dim3(FEAT / 64, n / 64, S), 256, 0, stream>>>(
            Tm, gb, pbuf, n, FEAT, n, n / S);
        comb_sum_abc_k<<<cgrid, 256, 0, stream>>>(pbuf, xnew, cle1W, cle1b, cle2W,
                                                  cle3W, cle3b, aar, bbr, cfr, nMN, S);
        fitness_k<<<n, 256, 0, stream>>>(Acur, aar, bbr, cfr, fit, n);
        topk_k<<<1, 1024, 0, stream>>>(fit, n, k, perm, fvals);
        gather_x_k<<<k, 256, 0, stream>>>(xnew, perm, fvals, xout);
        readout_part_k<<<k / 64, 256, 0, stream>>>(xout, psum, pmax, k, lvl * 16 * FEAT);
        if (lvl < 2) {
            gemm64_maskBp_part_k<<<dim3(n / 64, k / 64, 4), 256, 0, stream>>>(
                Tm, perm, Acur, pbuf, k, n, n, n / 4);
            comb_k<<<(k * n / 4) / 256, 256, 0, stream>>>(
                pbuf, Yb, nullptr, k * n, n, 4, 0);
            gemm64_ntp_part_k<<<dim3(k / 64, k / 64, 8), 256, 0, stream>>>(
                Yb, Tm, perm, pbuf, k, k, n, n / 8);
            comb_diag_deg_k<<<(k * k / 4) / 256, 256, 0, stream>>>(
                pbuf, Anext, dinv, k * k, k, 8);
        }
        const float* tswap = Acur;
        Acur = Anext;
        Anext = (float*)tswap;
        hcur = xout;
        n = k;
    }

    final_k<<<1, 256, 0, stream>>>(psum, pmax, cl1W, cl1b, cl2W, cl2b,
                                   (float*)d_out, out_size);
}

// Round 15
// 566.544 us; speedup vs baseline: 1.0320x; 1.0320x over previous
//
#include <hip/hip_runtime.h>

#define FEAT 256
#define NNODES 2048

// ---------------- reductions (blockDim.x == 256 required) ----------------
__device__ __forceinline__ float blk_sum(float v) {
    __shared__ float tmp[4];
    #pragma unroll
    for (int o = 32; o > 0; o >>= 1) v += __shfl_down(v, o, 64);
    __syncthreads();
    if ((threadIdx.x & 63) == 0) tmp[threadIdx.x >> 6] = v;
    __syncthreads();
    return tmp[0] + tmp[1] + tmp[2] + tmp[3];
}

__device__ __forceinline__ float blk_max(float v) {
    __shared__ float tmp[4];
    #pragma unroll
    for (int o = 32; o > 0; o >>= 1) v = fmaxf(v, __shfl_down(v, o, 64));
    __syncthreads();
    if ((threadIdx.x & 63) == 0) tmp[threadIdx.x >> 6] = v;
    __syncthreads();
    return fmaxf(fmaxf(tmp[0], tmp[1]), fmaxf(tmp[2], tmp[3]));
}

__device__ __forceinline__ float wave_sum(float v) {
    #pragma unroll
    for (int o = 32; o > 0; o >>= 1) v += __shfl_down(v, o, 64);
    return v;
}

__global__ void fill_zero_k(float* p, int n) {
    for (int i = blockIdx.x * 256 + threadIdx.x; i < n; i += gridDim.x * 256) p[i] = 0.f;
}

// =================== bitmask adjacency + CSR build (level 0) ===================
__global__ void scatter_bit_k(const int* ei, unsigned* bm, int n, int ne) {
    int e = blockIdx.x * 256 + threadIdx.x;
    if (e < ne) {
        size_t idx = (size_t)ei[e] * n + ei[ne + e];
        atomicOr(&bm[idx >> 5], 1u << (idx & 31));
    }
}

__global__ void countbits_k(const unsigned* bm, int* cnt, int n) {
    int j = blockIdx.x, t = threadIdx.x;
    int words = n / 32;
    int c = (t < words) ? __popc(bm[(size_t)j * words + t]) : 0;
    #pragma unroll
    for (int o = 32; o > 0; o >>= 1) c += __shfl_down(c, o, 64);
    if (t == 0) cnt[j] = c + 1;   // +1 diag
}

__global__ void csr_scan_k(const int* cnt, int* rowptr, float* dinv, int n) {
    __shared__ int part[256];
    int t = threadIdx.x;
    int per = n / 256;
    int loc[8];
    int s = 0;
    for (int i = 0; i < per; i++) {
        loc[i] = s;
        int c = cnt[t * per + i];
        s += c;
        dinv[t * per + i] = rsqrtf((float)c);
    }
    part[t] = s;
    __syncthreads();
    for (int off = 1; off < 256; off <<= 1) {
        int v = (t >= off) ? part[t - off] : 0;
        __syncthreads();
        part[t] += v;
        __syncthreads();
    }
    int ex = (t == 0) ? 0 : part[t - 1];
    for (int i = 0; i < per; i++) rowptr[t * per + i] = ex + loc[i];
    if (t == 255) rowptr[n] = part[255];
}

__global__ void fillcsr_bits_k(const unsigned* bm, const int* rowptr, int* cols, int n) {
    int j = blockIdx.x, t = threadIdx.x;
    int words = n / 32;
    unsigned w = (t < words) ? bm[(size_t)j * words + t] : 0u;
    int c = __popc(w);
    int incl = c;
    #pragma unroll
    for (int o = 1; o < 64; o <<= 1) {
        int x = __shfl_up(incl, o, 64);
        if (t >= o) incl += x;
    }
    int base = rowptr[j] + 1 + (incl - c);
    if (t == 0) cols[rowptr[j]] = j;
    while (w) {
        int b = __ffs(w) - 1;
        cols[base++] = t * 32 + b;
        w &= w - 1;
    }
}

// =================== level-0 sparse kernels ===================
// + fused v[j] = dot(out_row_j, attw[256:512])
__global__ void sparse_gcn_k(const int* rowptr, const int* cols, const float* dinv,
                             const float* xW, const float* bias,
                             const float* attw, float* v, float* out) {
    int j = blockIdx.x, c = threadIdx.x;
    int r0 = rowptr[j], r1 = rowptr[j + 1];
    __shared__ int scol[256];
    __shared__ float sdv[256];
    float s = 0.f;
    for (int e0 = r0; e0 < r1; e0 += 256) {
        int m = min(256, r1 - e0);
        __syncthreads();
        if (c < m) { int ci = cols[e0 + c]; scol[c] = ci; sdv[c] = dinv[ci]; }
        __syncthreads();
        #pragma unroll 4
        for (int ii = 0; ii < m; ii++) s += sdv[ii] * xW[(size_t)scol[ii] * FEAT + c];
    }
    float o = fmaxf(dinv[j] * s + bias[c], 0.f);
    out[(size_t)j * FEAT + c] = o;
    float sv = blk_sum(o * attw[FEAT + c]);
    if (c == 0) v[j] = sv;
}

__global__ void sparse_mmax_k(const int* rowptr, const int* cols, const float* g, float* out) {
    int j = blockIdx.x, c = threadIdx.x;
    int r0 = rowptr[j], r1 = rowptr[j + 1];
    __shared__ int scol[256];
    float mv = -3.402823466e38f;
    for (int e0 = r0; e0 < r1; e0 += 256) {
        int m = min(256, r1 - e0);
        __syncthreads();
        if (c < m) scol[c] = cols[e0 + c];
        __syncthreads();
        #pragma unroll 4
        for (int ii = 0; ii < m; ii++) mv = fmaxf(mv, g[(size_t)scol[ii] * FEAT + c]);
    }
    out[(size_t)j * FEAT + c] = mv;
}

// + fused u[j] = dot(xq_row_j, attw[0:256]) (coalesced row read, u_k eliminated)
__global__ void sparse_score_k(const int* rowptr, const int* cols, const float* xq,
                               const float* attw, const float* v, const float* attb,
                               float* sval) {
    int j = blockIdx.x;
    int r0 = rowptr[j], r1 = rowptr[j + 1];
    float uj = blk_sum(xq[(size_t)j * FEAT + threadIdx.x] * attw[threadIdx.x]) + attb[0];
    float mx = -3.402823466e38f;
    for (int e = r0 + threadIdx.x; e < r1; e += 256) {
        float r = v[cols[e]] + uj;
        r = (r >= 0.f) ? r : 0.2f * r;
        mx = fmaxf(mx, r);
    }
    mx = blk_max(mx);
    float sum = 0.f;
    for (int e = r0 + threadIdx.x; e < r1; e += 256) {
        float r = v[cols[e]] + uj;
        r = (r >= 0.f) ? r : 0.2f * r;
        sum += expf(r - mx);
    }
    sum = blk_sum(sum);
    for (int e = r0 + threadIdx.x; e < r1; e += 256) {
        float r = v[cols[e]] + uj;
        r = (r >= 0.f) ? r : 0.2f * r;
        sval[e] = expf(r - mx) / sum;
    }
}

// + fused a/bb/cf row dots
__global__ void sparse_xnew_k(const int* rowptr, const int* cols, const float* sval,
                              const float* g,
                              const float* w1, const float* b1, const float* w2,
                              const float* w3, const float* b3,
                              float* a, float* bb, float* cf, float* xnew) {
    int j = blockIdx.x, c = threadIdx.x;
    int r0 = rowptr[j], r1 = rowptr[j + 1];
    __shared__ int scol[256];
    __shared__ float sv[256];
    float s = 0.f;
    for (int e0 = r0; e0 < r1; e0 += 256) {
        int m = min(256, r1 - e0);
        __syncthreads();
        if (c < m) { scol[c] = cols[e0 + c]; sv[c] = sval[e0 + c]; }
        __syncthreads();
        #pragma unroll 4
        for (int ii = 0; ii < m; ii++) s += sv[ii] * g[(size_t)scol[ii] * FEAT + c];
    }
    xnew[(size_t)j * FEAT + c] = s;
    float s1 = blk_sum(s * w1[c]);
    float s2 = blk_sum(s * w2[c]);
    float s3 = blk_sum(s * w3[c]);
    if (c == 0) { a[j] = s1 + b1[0]; bb[j] = s2; cf[j] = s3 + b3[0]; }
}

__global__ void sparse_fitness_k(const int* rowptr, const int* cols, const float* a,
                                 const float* bb, const float* cf, float* fit) {
    int j = blockIdx.x;
    int r0 = rowptr[j], r1 = rowptr[j + 1];
    float s = 0.f;
    for (int e = r0 + threadIdx.x; e < r1; e += 256) s += a[cols[e]];
    s = blk_sum(s);
    if (threadIdx.x == 0) {
        float z = s - (float)(r1 - r0) * bb[j] + cf[j];
        fit[j] = 1.f / (1.f + expf(-z));
    }
}

__global__ void sp_fill_k(const int* rowptr, const int* cols, const float* sval,
                          const int* perm, float* Sp, int kw) {
    int q = blockIdx.x;
    int row = perm[q];
    int r0 = rowptr[row], r1 = rowptr[row + 1];
    for (int e = r0 + threadIdx.x; e < r1; e += 256)
        Sp[(size_t)cols[e] * kw + q] = sval[e];
}

__global__ void z_k(const int* rowptr, const int* cols, const float* Sp, float* Z, int kw) {
    int j = blockIdx.x;
    int c4 = threadIdx.x * 4;
    int r0 = rowptr[j], r1 = rowptr[j + 1];
    __shared__ int scol[256];
    float4 acc = {0.f, 0.f, 0.f, 0.f};
    for (int e0 = r0; e0 < r1; e0 += 256) {
        int m = min(256, r1 - e0);
        __syncthreads();
        if (threadIdx.x < m) scol[threadIdx.x] = cols[e0 + threadIdx.x];
        __syncthreads();
        #pragma unroll 4
        for (int ii = 0; ii < m; ii++) {
            float4 s = *(const float4*)&Sp[(size_t)scol[ii] * kw + c4];
            acc.x += s.x; acc.y += s.y; acc.z += s.z; acc.w += s.w;
        }
    }
    *(float4*)&Z[(size_t)j * kw + c4] = acc;
}

// ac_k + fused row-sum -> dinv for the next level
__global__ void ac_k(const int* rowptr, const int* cols, const float* sval,
                     const int* perm, const float* Z, float* Aout, float* dinv, int kw) {
    int p = blockIdx.x;
    int row = perm[p];
    int c4 = threadIdx.x * 4;
    int r0 = rowptr[row], r1 = rowptr[row + 1];
    __shared__ int scol[256];
    __shared__ float sv[256];
    float4 acc = {0.f, 0.f, 0.f, 0.f};
    for (int e0 = r0; e0 < r1; e0 += 256) {
        int m = min(256, r1 - e0);
        __syncthreads();
        if (threadIdx.x < m) { scol[threadIdx.x] = cols[e0 + threadIdx.x]; sv[threadIdx.x] = sval[e0 + threadIdx.x]; }
        __syncthreads();
        #pragma unroll 4
        for (int ii = 0; ii < m; ii++) {
            float w = sv[ii];
            float4 z = *(const float4*)&Z[(size_t)scol[ii] * kw + c4];
            acc.x += w * z.x; acc.y += w * z.y; acc.z += w * z.z; acc.w += w * z.w;
        }
    }
    if (p >= c4 && p < c4 + 4) ((float*)&acc)[p - c4] = 0.f;
    *(float4*)&Aout[(size_t)p * kw + c4] = acc;
    __syncthreads();
    float ps = blk_sum(acc.x + acc.y + acc.z + acc.w);
    if (threadIdx.x == 0) dinv[p] = rsqrtf(ps + 1.0f);
}

// =================== 64x64-tile dense f32 GEMMs (full + split-K parts) ===================
#define LDT 68

__global__ __launch_bounds__(256) void gemm64_nn_k(const float* A, const float* B,
                                                   const float* bias, float* C,
                                                   int M, int N, int K) {
    __shared__ float As[16][LDT];
    __shared__ float Bs[16][LDT];
    int t = threadIdx.x;
    int tx = t & 15, ty = t >> 4;
    int ar = t >> 2, akq = t & 3;
    int bkr = t >> 4, bcq = t & 15;
    const float* Ab = A + (size_t)(blockIdx.y * 64 + ar) * K + akq * 4;
    const float* Bb = B + (size_t)bkr * N + blockIdx.x * 64 + bcq * 4;
    float acc[4][4] = {};
    for (int k0 = 0; k0 < K; k0 += 16) {
        float4 av = *(const float4*)(Ab + k0);
        float4 bv = *(const float4*)(Bb + (size_t)k0 * N);
        As[akq * 4 + 0][ar] = av.x; As[akq * 4 + 1][ar] = av.y;
        As[akq * 4 + 2][ar] = av.z; As[akq * 4 + 3][ar] = av.w;
        *(float4*)&Bs[bkr][bcq * 4] = bv;
        __syncthreads();
        #pragma unroll
        for (int kk = 0; kk < 16; kk++) {
            float4 a = *(const float4*)&As[kk][ty * 4];
            float4 b = *(const float4*)&Bs[kk][tx * 4];
            acc[0][0] += a.x * b.x; acc[0][1] += a.x * b.y; acc[0][2] += a.x * b.z; acc[0][3] += a.x * b.w;
            acc[1][0] += a.y * b.x; acc[1][1] += a.y * b.y; acc[1][2] += a.y * b.z; acc[1][3] += a.y * b.w;
            acc[2][0] += a.z * b.x; acc[2][1] += a.z * b.y; acc[2][2] += a.z * b.z; acc[2][3] += a.z * b.w;
            acc[3][0] += a.w * b.x; acc[3][1] += a.w * b.y; acc[3][2] += a.w * b.z; acc[3][3] += a.w * b.w;
        }
        __syncthreads();
    }
    int cb = blockIdx.x * 64 + tx * 4;
    float4 bv = {0.f, 0.f, 0.f, 0.f};
    if (bias) bv = *(const float4*)&bias[cb];
    #pragma unroll
    for (int i = 0; i < 4; i++) {
        int row = blockIdx.y * 64 + ty * 4 + i;
        float4 o = {acc[i][0] + bv.x, acc[i][1] + bv.y, acc[i][2] + bv.z, acc[i][3] + bv.w};
        *(float4*)&C[(size_t)row * N + cb] = o;
    }
}

__global__ __launch_bounds__(256) void gemm64_nn_part_k(const float* A, const float* B,
                                                        float* part, int M, int N, int K,
                                                        int kch) {
    __shared__ float As[16][LDT];
    __shared__ float Bs[16][LDT];
    int t = threadIdx.x;
    int tx = t & 15, ty = t >> 4;
    int ar = t >> 2, akq = t & 3;
    int bkr = t >> 4, bcq = t & 15;
    int ks = blockIdx.z * kch;
    const float* Ab = A + (size_t)(blockIdx.y * 64 + ar) * K + akq * 4;
    const float* Bb = B + (size_t)bkr * N + blockIdx.x * 64 + bcq * 4;
    float acc[4][4] = {};
    for (int k0 = ks; k0 < ks + kch; k0 += 16) {
        float4 av = *(const float4*)(Ab + k0);
        float4 bv = *(const float4*)(Bb + (size_t)k0 * N);
        As[akq * 4 + 0][ar] = av.x; As[akq * 4 + 1][ar] = av.y;
        As[akq * 4 + 2][ar] = av.z; As[akq * 4 + 3][ar] = av.w;
        *(float4*)&Bs[bkr][bcq * 4] = bv;
        __syncthreads();
        #pragma unroll
        for (int kk = 0; kk < 16; kk++) {
            float4 a = *(const float4*)&As[kk][ty * 4];
            float4 b = *(const float4*)&Bs[kk][tx * 4];
            acc[0][0] += a.x * b.x; acc[0][1] += a.x * b.y; acc[0][2] += a.x * b.z; acc[0][3] += a.x * b.w;
            acc[1][0] += a.y * b.x; acc[1][1] += a.y * b.y; acc[1][2] += a.y * b.z; acc[1][3] += a.y * b.w;
            acc[2][0] += a.z * b.x; acc[2][1] += a.z * b.y; acc[2][2] += a.z * b.z; acc[2][3] += a.z * b.w;
            acc[3][0] += a.w * b.x; acc[3][1] += a.w * b.y; acc[3][2] += a.w * b.z; acc[3][3] += a.w * b.w;
        }
        __syncthreads();
    }
    int cb = blockIdx.x * 64 + tx * 4;
    float* out = part + (size_t)blockIdx.z * M * N;
    #pragma unroll
    for (int i = 0; i < 4; i++) {
        int row = blockIdx.y * 64 + ty * 4 + i;
        float4 o = {acc[i][0], acc[i][1], acc[i][2], acc[i][3]};
        *(float4*)&out[(size_t)row * N + cb] = o;
    }
}

__global__ __launch_bounds__(256) void gcn64_part_k(const float* A, const float* dinv,
                                                    const float* xW, float* part,
                                                    int n, int kch) {
    __shared__ float As[16][LDT];
    __shared__ float Bs[16][LDT];
    int t = threadIdx.x;
    int tx = t & 15, ty = t >> 4;
    int ar = t >> 2, akq = t & 3;
    int bkr = t >> 4, bcq = t & 15;
    int arow = blockIdx.y * 64 + ar;
    int ks = blockIdx.z * kch;
    const float* Ab = A + (size_t)arow * n + akq * 4;
    const float* Bb = xW + (size_t)bkr * FEAT + blockIdx.x * 64 + bcq * 4;
    float acc[4][4] = {};
    float dj = dinv[arow];
    for (int k0 = ks; k0 < ks + kch; k0 += 16) {
        int ibase = k0 + akq * 4;
        float4 av = *(const float4*)(Ab + k0);
        float4 dv = *(const float4*)&dinv[ibase];
        As[akq * 4 + 0][ar] = (ibase + 0 == arow) ? dj : av.x * dv.x;
        As[akq * 4 + 1][ar] = (ibase + 1 == arow) ? dj : av.y * dv.y;
        As[akq * 4 + 2][ar] = (ibase + 2 == arow) ? dj : av.z * dv.z;
        As[akq * 4 + 3][ar] = (ibase + 3 == arow) ? dj : av.w * dv.w;
        float4 bv = *(const float4*)(Bb + (size_t)k0 * FEAT);
        *(float4*)&Bs[bkr][bcq * 4] = bv;
        __syncthreads();
        #pragma unroll
        for (int kk = 0; kk < 16; kk++) {
            float4 a = *(const float4*)&As[kk][ty * 4];
            float4 b = *(const float4*)&Bs[kk][tx * 4];
            acc[0][0] += a.x * b.x; acc[0][1] += a.x * b.y; acc[0][2] += a.x * b.z; acc[0][3] += a.x * b.w;
            acc[1][0] += a.y * b.x; acc[1][1] += a.y * b.y; acc[1][2] += a.y * b.z; acc[1][3] += a.y * b.w;
            acc[2][0] += a.z * b.x; acc[2][1] += a.z * b.y; acc[2][2] += a.z * b.z; acc[2][3] += a.z * b.w;
            acc[3][0] += a.w * b.x; acc[3][1] += a.w * b.y; acc[3][2] += a.w * b.z; acc[3][3] += a.w * b.w;
        }
        __syncthreads();
    }
    int cb = blockIdx.x * 64 + tx * 4;
    float* out = part + (size_t)blockIdx.z * n * FEAT;
    #pragma unroll
    for (int i = 0; i < 4; i++) {
        int row = blockIdx.y * 64 + ty * 4 + i;
        float4 o = {acc[i][0], acc[i][1], acc[i][2], acc[i][3]};
        *(float4*)&out[(size_t)row * FEAT + cb] = o;
    }
}

__global__ __launch_bounds__(256) void mmax64_part_k(const float* A, const float* g,
                                                     float* part, int n, int kch) {
    __shared__ float As[16][LDT];
    __shared__ float Bs[16][LDT];
    int t = threadIdx.x;
    int tx = t & 15, ty = t >> 4;
    int ar = t >> 2, akq = t & 3;
    int bkr = t >> 4, bcq = t & 15;
    int arow = blockIdx.y * 64 + ar;
    int ks = blockIdx.z * kch;
    const float* Ab = A + (size_t)arow * n + akq * 4;
    const float* Bb = g + (size_t)bkr * FEAT + blockIdx.x * 64 + bcq * 4;
    const float NEG = -3.402823466e38f;
    float acc[4][4] = {{NEG, NEG, NEG, NEG}, {NEG, NEG, NEG, NEG},
                       {NEG, NEG, NEG, NEG}, {NEG, NEG, NEG, NEG}};
    for (int k0 = ks; k0 < ks + kch; k0 += 16) {
        int ibase = k0 + akq * 4;
        float4 av = *(const float4*)(Ab + k0);
        As[akq * 4 + 0][ar] = (av.x != 0.f || ibase + 0 == arow) ? 0.f : NEG;
        As[akq * 4 + 1][ar] = (av.y != 0.f || ibase + 1 == arow) ? 0.f : NEG;
        As[akq * 4 + 2][ar] = (av.z != 0.f || ibase + 2 == arow) ? 0.f : NEG;
        As[akq * 4 + 3][ar] = (av.w != 0.f || ibase + 3 == arow) ? 0.f : NEG;
        float4 bv = *(const float4*)(Bb + (size_t)k0 * FEAT);
        *(float4*)&Bs[bkr][bcq * 4] = bv;
        __syncthreads();
        #pragma unroll
        for (int kk = 0; kk < 16; kk++) {
            float4 a = *(const float4*)&As[kk][ty * 4];
            float4 b = *(const float4*)&Bs[kk][tx * 4];
            acc[0][0] = fmaxf(acc[0][0], b.x + a.x); acc[0][1] = fmaxf(acc[0][1], b.y + a.x);
            acc[0][2] = fmaxf(acc[0][2], b.z + a.x); acc[0][3] = fmaxf(acc[0][3], b.w + a.x);
            acc[1][0] = fmaxf(acc[1][0], b.x + a.y); acc[1][1] = fmaxf(acc[1][1], b.y + a.y);
            acc[1][2] = fmaxf(acc[1][2], b.z + a.y); acc[1][3] = fmaxf(acc[1][3], b.w + a.y);
            acc[2][0] = fmaxf(acc[2][0], b.x + a.z); acc[2][1] = fmaxf(acc[2][1], b.y + a.z);
            acc[2][2] = fmaxf(acc[2][2], b.z + a.z); acc[2][3] = fmaxf(acc[2][3], b.w + a.z);
            acc[3][0] = fmaxf(acc[3][0], b.x + a.w); acc[3][1] = fmaxf(acc[3][1], b.y + a.w);
            acc[3][2] = fmaxf(acc[3][2], b.z + a.w); acc[3][3] = fmaxf(acc[3][3], b.w + a.w);
        }
        __syncthreads();
    }
    int cb = blockIdx.x * 64 + tx * 4;
    float* out = part + (size_t)blockIdx.z * n * FEAT;
    #pragma unroll
    for (int i = 0; i < 4; i++) {
        int row = blockIdx.y * 64 + ty * 4 + i;
        float4 o = {acc[i][0], acc[i][1], acc[i][2], acc[i][3]};
        *(float4*)&out[(size_t)row * FEAT + cb] = o;
    }
}

// A rows read through perm: A_logical[row] = A[perm[row]]
__global__ __launch_bounds__(256) void gemm64_maskBp_part_k(const float* A, const int* perm,
                                                            const float* Adj, float* part,
                                                            int M, int N, int K, int kch) {
    __shared__ float As[16][LDT];
    __shared__ float Bs[16][LDT];
    int t = threadIdx.x;
    int tx = t & 15, ty = t >> 4;
    int ar = t >> 2, akq = t & 3;
    int bkr = t >> 4, bcq = t & 15;
    int ks = blockIdx.z * kch;
    const float* Ab = A + (size_t)perm[blockIdx.y * 64 + ar] * K + akq * 4;
    int cbase = blockIdx.x * 64 + bcq * 4;
    float acc[4][4] = {};
    for (int k0 = ks; k0 < ks + kch; k0 += 16) {
        float4 av = *(const float4*)(Ab + k0);
        int brow = k0 + bkr;
        float4 adj = *(const float4*)&Adj[(size_t)brow * N + cbase];
        As[akq * 4 + 0][ar] = av.x; As[akq * 4 + 1][ar] = av.y;
        As[akq * 4 + 2][ar] = av.z; As[akq * 4 + 3][ar] = av.w;
        Bs[bkr][bcq * 4 + 0] = (adj.x != 0.f || brow == cbase + 0) ? 1.f : 0.f;
        Bs[bkr][bcq * 4 + 1] = (adj.y != 0.f || brow == cbase + 1) ? 1.f : 0.f;
        Bs[bkr][bcq * 4 + 2] = (adj.z != 0.f || brow == cbase + 2) ? 1.f : 0.f;
        Bs[bkr][bcq * 4 + 3] = (adj.w != 0.f || brow == cbase + 3) ? 1.f : 0.f;
        __syncthreads();
        #pragma unroll
        for (int kk = 0; kk < 16; kk++) {
            float4 a = *(const float4*)&As[kk][ty * 4];
            float4 b = *(const float4*)&Bs[kk][tx * 4];
            acc[0][0] += a.x * b.x; acc[0][1] += a.x * b.y; acc[0][2] += a.x * b.z; acc[0][3] += a.x * b.w;
            acc[1][0] += a.y * b.x; acc[1][1] += a.y * b.y; acc[1][2] += a.y * b.z; acc[1][3] += a.y * b.w;
            acc[2][0] += a.z * b.x; acc[2][1] += a.z * b.y; acc[2][2] += a.z * b.z; acc[2][3] += a.z * b.w;
            acc[3][0] += a.w * b.x; acc[3][1] += a.w * b.y; acc[3][2] += a.w * b.z; acc[3][3] += a.w * b.w;
        }
        __syncthreads();
    }
    int cb = blockIdx.x * 64 + tx * 4;
    float* out = part + (size_t)blockIdx.z * M * N;
    #pragma unroll
    for (int i = 0; i < 4; i++) {
        int row = blockIdx.y * 64 + ty * 4 + i;
        float4 o = {acc[i][0], acc[i][1], acc[i][2], acc[i][3]};
        *(float4*)&out[(size_t)row * N + cb] = o;
    }
}

// B rows read through perm: B_logical[col] = B[perm[col]]
__global__ __launch_bounds__(256) void gemm64_ntp_part_k(const float* A, const float* B,
                                                         const int* perm, float* part,
                                                         int M, int N, int K, int kch) {
    __shared__ float As[16][LDT];
    __shared__ float Bs[16][LDT];
    int t = threadIdx.x;
    int tx = t & 15, ty = t >> 4;
    int ar = t >> 2, akq = t & 3;
    int ks = blockIdx.z * kch;
    const float* Ab = A + (size_t)(blockIdx.y * 64 + ar) * K + akq * 4;
    const float* Bb = B + (size_t)perm[blockIdx.x * 64 + ar] * K + akq * 4;
    float acc[4][4] = {};
    for (int k0 = ks; k0 < ks + kch; k0 += 16) {
        float4 av = *(const float4*)(Ab + k0);
        float4 bv = *(const float4*)(Bb + k0);
        As[akq * 4 + 0][ar] = av.x; As[akq * 4 + 1][ar] = av.y;
        As[akq * 4 + 2][ar] = av.z; As[akq * 4 + 3][ar] = av.w;
        Bs[akq * 4 + 0][ar] = bv.x; Bs[akq * 4 + 1][ar] = bv.y;
        Bs[akq * 4 + 2][ar] = bv.z; Bs[akq * 4 + 3][ar] = bv.w;
        __syncthreads();
        #pragma unroll
        for (int kk = 0; kk < 16; kk++) {
            float4 a = *(const float4*)&As[kk][ty * 4];
            float4 b = *(const float4*)&Bs[kk][tx * 4];
            acc[0][0] += a.x * b.x; acc[0][1] += a.x * b.y; acc[0][2] += a.x * b.z; acc[0][3] += a.x * b.w;
            acc[1][0] += a.y * b.x; acc[1][1] += a.y * b.y; acc[1][2] += a.y * b.z; acc[1][3] += a.y * b.w;
            acc[2][0] += a.z * b.x; acc[2][1] += a.z * b.y; acc[2][2] += a.z * b.z; acc[2][3] += a.z * b.w;
            acc[3][0] += a.w * b.x; acc[3][1] += a.w * b.y; acc[3][2] += a.w * b.z; acc[3][3] += a.w * b.w;
        }
        __syncthreads();
    }
    int cb = blockIdx.x * 64 + tx * 4;
    float* out = part + (size_t)blockIdx.z * M * N;
    #pragma unroll
    for (int i = 0; i < 4; i++) {
        int row = blockIdx.y * 64 + ty * 4 + i;
        float4 o = {acc[i][0], acc[i][1], acc[i][2], acc[i][3]};
        *(float4*)&out[(size_t)row * N + cb] = o;
    }
}

// ---------------- comb variants ----------------
__global__ void comb_k(const float* part, float* out, const float* bias,
                       int MN, int N, int S, int mode) {
    int i4 = (blockIdx.x * 256 + threadIdx.x) * 4;
    if (i4 >= MN) return;
    float4 v;
    if (mode == 1) {
        v = *(const float4*)&part[i4];
        for (int s = 1; s < S; s++) {
            float4 p = *(const float4*)&part[(size_t)s * MN + i4];
            v.x = fmaxf(v.x, p.x); v.y = fmaxf(v.y, p.y);
            v.z = fmaxf(v.z, p.z); v.w = fmaxf(v.w, p.w);
        }
    } else {
        v = make_float4(0.f, 0.f, 0.f, 0.f);
        for (int s = 0; s < S; s++) {
            float4 p = *(const float4*)&part[(size_t)s * MN + i4];
            v.x += p.x; v.y += p.y; v.z += p.z; v.w += p.w;
        }
        if (bias) {
            int col = i4 % N;
            float4 bv = *(const float4*)&bias[col];
            v.x += bv.x; v.y += bv.y; v.z += bv.z; v.w += bv.w;
        }
    }
    *(float4*)&out[i4] = v;
}

__global__ void comb_relu_v_k(const float* part, float* out, const float* bias,
                              const float* dinv, const float* attw, float* v,
                              int MN, int S) {
    int t = threadIdx.x;
    int i4 = (blockIdx.x * 256 + t) * 4;
    float4 s = make_float4(0.f, 0.f, 0.f, 0.f);
    for (int ss = 0; ss < S; ss++) {
        float4 p = *(const float4*)&part[(size_t)ss * MN + i4];
        s.x += p.x; s.y += p.y; s.z += p.z; s.w += p.w;
    }
    int row = i4 >> 8;
    int col = i4 & 255;
    float dj = dinv[row];
    float4 bv = *(const float4*)&bias[col];
    float4 o = {fmaxf(dj * s.x + bv.x, 0.f), fmaxf(dj * s.y + bv.y, 0.f),
                fmaxf(dj * s.z + bv.z, 0.f), fmaxf(dj * s.w + bv.w, 0.f)};
    *(float4*)&out[i4] = o;
    float4 aw = *(const float4*)&attw[256 + col];
    float pv = wave_sum(o.x * aw.x + o.y * aw.y + o.z * aw.z + o.w * aw.w);
    if ((t & 63) == 0) v[row] = pv;
}

__global__ void comb_sum_u_k(const float* part, float* out, const float* bias,
                             const float* attw, float* u, int MN, int S) {
    int t = threadIdx.x;
    int i4 = (blockIdx.x * 256 + t) * 4;
    float4 s = make_float4(0.f, 0.f, 0.f, 0.f);
    for (int ss = 0; ss < S; ss++) {
        float4 p = *(const float4*)&part[(size_t)ss * MN + i4];
        s.x += p.x; s.y += p.y; s.z += p.z; s.w += p.w;
    }
    int row = i4 >> 8;
    int col = i4 & 255;
    float4 bv = *(const float4*)&bias[col];
    float4 o = {s.x + bv.x, s.y + bv.y, s.z + bv.z, s.w + bv.w};
    *(float4*)&out[i4] = o;
    float4 aw = *(const float4*)&attw[col];
    float pu = wave_sum(o.x * aw.x + o.y * aw.y + o.z * aw.z + o.w * aw.w);
    if ((t & 63) == 0) u[row] = pu;
}

__global__ void comb_sum_abc_k(const float* part, float* out,
                               const float* w1, const float* b1, const float* w2,
                               const float* w3, const float* b3,
                               float* a, float* bb, float* cf, int MN, int S) {
    int t = threadIdx.x;
    int i4 = (blockIdx.x * 256 + t) * 4;
    float4 s = make_float4(0.f, 0.f, 0.f, 0.f);
    for (int ss = 0; ss < S; ss++) {
        float4 p = *(const float4*)&part[(size_t)ss * MN + i4];
        s.x += p.x; s.y += p.y; s.z += p.z; s.w += p.w;
    }
    *(float4*)&out[i4] = s;
    int row = i4 >> 8;
    int col = i4 & 255;
    float4 v1 = *(const float4*)&w1[col];
    float4 v2 = *(const float4*)&w2[col];
    float4 v3 = *(const float4*)&w3[col];
    float p1 = wave_sum(s.x * v1.x + s.y * v1.y + s.z * v1.z + s.w * v1.w);
    float p2 = wave_sum(s.x * v2.x + s.y * v2.y + s.z * v2.z + s.w * v2.w);
    float p3 = wave_sum(s.x * v3.x + s.y * v3.y + s.z * v3.z + s.w * v3.w);
    if ((t & 63) == 0) {
        a[row] = p1 + b1[0];
        bb[row] = p2;
        cf[row] = p3 + b3[0];
    }
}

__global__ void comb_diag_deg_k(const float* part, float* out, float* dinv,
                                int MN, int N, int S) {
    int t = threadIdx.x;
    int i4 = (blockIdx.x * 256 + t) * 4;
    float4 s = make_float4(0.f, 0.f, 0.f, 0.f);
    for (int ss = 0; ss < S; ss++) {
        float4 p = *(const float4*)&part[(size_t)ss * MN + i4];
        s.x += p.x; s.y += p.y; s.z += p.z; s.w += p.w;
    }
    int row = i4 / N, col = i4 % N;
    if (row >= col && row < col + 4) ((float*)&s)[row - col] = 0.f;
    *(float4*)&out[i4] = s;
    float ps = wave_sum(s.x + s.y + s.z + s.w);
    __shared__ float rsum[4];
    if ((t & 63) == 0) rsum[t >> 6] = ps;
    __syncthreads();
    if (t == 0) dinv[row] = rsqrtf(rsum[0] + rsum[1] + 1.0f);
    if (t == 128) dinv[row] = rsqrtf(rsum[2] + rsum[3] + 1.0f);
}

// =================== per-row kernels ===================
__global__ void score_k(const float* A, const float* u, const float* v, const float* attb,
                        float* T, int n) {
    int j = blockIdx.x;
    float uj = u[j] + attb[0];
    float mx = -3.402823466e38f;
    for (int i = threadIdx.x; i < n; i += 256) {
        bool msk = (i == j) || (A[(size_t)j * n + i] != 0.f);
        float r = v[i] + uj;
        r = (r >= 0.f) ? r : 0.2f * r;
        mx = fmaxf(mx, msk ? r : -3.402823466e38f);
    }
    mx = blk_max(mx);
    float sum = 0.f;
    for (int i = threadIdx.x; i < n; i += 256) {
        bool msk = (i == j) || (A[(size_t)j * n + i] != 0.f);
        float r = v[i] + uj;
        r = (r >= 0.f) ? r : 0.2f * r;
        sum += msk ? expf(r - mx) : 0.f;
    }
    sum = blk_sum(sum);
    for (int i = threadIdx.x; i < n; i += 256) {
        bool msk = (i == j) || (A[(size_t)j * n + i] != 0.f);
        float r = v[i] + uj;
        r = (r >= 0.f) ? r : 0.2f * r;
        T[(size_t)j * n + i] = msk ? (expf(r - mx) / sum) : 0.f;
    }
}

__global__ void fitness_k(const float* A, const float* a, const float* bb, const float* cf,
                          float* fit, int n) {
    int j = blockIdx.x;
    float s = 0.f, d = 0.f;
    for (int i = threadIdx.x; i < n; i += 256) {
        bool msk = (i == j) || (A[(size_t)j * n + i] != 0.f);
        float av = a[i];
        s += msk ? av : 0.f;
        d += msk ? 1.f : 0.f;
    }
    s = blk_sum(s);
    d = blk_sum(d);
    if (threadIdx.x == 0) {
        float z = s - d * bb[j] + cf[j];
        fit[j] = 1.f / (1.f + expf(-z));
    }
}

__global__ void topk_k(const float* fitv, int n, int k, int* perm, float* fvals) {
    __shared__ float sf[2048];
    __shared__ int si[2048];
    for (int i = threadIdx.x; i < n; i += blockDim.x) { sf[i] = fitv[i]; si[i] = i; }
    __syncthreads();
    for (int sz = 2; sz <= n; sz <<= 1) {
        for (int st = sz >> 1; st > 0; st >>= 1) {
            for (int i = threadIdx.x; i < n; i += blockDim.x) {
                int jj = i ^ st;
                if (jj > i) {
                    bool up = ((i & sz) == 0);
                    float fi_ = sf[i], fj_ = sf[jj];
                    int ii_ = si[i], ij_ = si[jj];
                    bool before = (fi_ > fj_) || (fi_ == fj_ && ii_ < ij_);
                    if (up ? !before : before) {
                        sf[i] = fj_; sf[jj] = fi_;
                        si[i] = ij_; si[jj] = ii_;
                    }
                }
            }
            __syncthreads();
        }
    }
    for (int i = threadIdx.x; i < k; i += blockDim.x) { perm[i] = si[i]; fvals[i] = sf[i]; }
}

__global__ void gather_x_k(const float* xnew, const int* perm, const float* fvals, float* xout) {
    int p = blockIdx.x, c = threadIdx.x;
    xout[(size_t)p * FEAT + c] = xnew[(size_t)perm[p] * FEAT + c] * fvals[p];
}

__global__ void readout_part_k(const float* h, float* psum, float* pmax, int k, int lvl_off) {
    int b = blockIdx.x, c = threadIdx.x;
    int r0 = b * 64, r1 = min(r0 + 64, k);
    float s = 0.f, m = -3.402823466e38f;
    for (int j = r0; j < r1; j++) {
        float x = h[(size_t)j * FEAT + c];
        s += x;
        m = fmaxf(m, x);
    }
    psum[lvl_off + b * FEAT + c] = s;
    pmax[lvl_off + b * FEAT + c] = m;
}

__global__ void final_k(const float* psum, const float* pmax,
                        const float* l1W, const float* l1b,
                        const float* l2W, const float* l2b, float* out, int osz) {
    __shared__ float ro[512];
    __shared__ float hid[256];
    __shared__ float logits[10];
    int c = threadIdx.x;
    const int nb[3] = {16, 8, 4};
    const float kl[3] = {1024.f, 512.f, 256.f};
    float st = 0.f, mt = 0.f;
    for (int l = 0; l < 3; l++) {
        float s = 0.f, m = -3.402823466e38f;
        int off = l * 16 * FEAT;
        for (int b = 0; b < nb[l]; b++) {
            s += psum[off + b * FEAT + c];
            m = fmaxf(m, pmax[off + b * FEAT + c]);
        }
        st += s / kl[l];
        mt += m;
    }
    ro[c] = st;
    ro[FEAT + c] = mt;
    __syncthreads();
    float s = l1b[c];
    for (int kk = 0; kk < 512; kk++) s += ro[kk] * l1W[(size_t)kk * 256 + c];
    hid[c] = fmaxf(s, 0.f);
    __syncthreads();
    if (c < 10) {
        float t = l2b[c];
        for (int kk = 0; kk < 256; kk++) t += hid[kk] * l2W[(size_t)kk * 10 + c];
        logits[c] = t;
    }
    __syncthreads();
    if (c == 0) {
        float mx = -3.402823466e38f;
        for (int i = 0; i < 10; i++) mx = fmaxf(mx, logits[i]);
        float se = 0.f;
        for (int i = 0; i < 10; i++) se += expf(logits[i] - mx);
        float lse = mx + logf(se);
        for (int i = 0; i < osz && i < 10; i++) out[i] = logits[i] - lse;
    }
}

// ---------------- host ----------------
extern "C" void kernel_launch(void* const* d_in, const int* in_sizes, int n_in,
                              void* d_out, int out_size, void* d_ws, size_t ws_size,
                              hipStream_t stream) {
    (void)n_in; (void)ws_size;
    float* base = (float*)d_ws;
    size_t off = 0;
    auto alloc = [&](size_t cnt) { float* p = base + off; off += cnt; return p; };

    float* A_a   = alloc((size_t)1024 * 1024);
    float* A_b   = alloc((size_t)1024 * 1024);
    float* Tm    = alloc((size_t)1024 * 1024);
    float* Yb    = alloc((size_t)512 * 1024);
    float* Sp    = alloc((size_t)2048 * 1024);
    float* Zb    = alloc((size_t)2048 * 1024);
    float* pbuf  = alloc((size_t)8 * 1024 * 256);
    float* xW    = alloc((size_t)2048 * 256);
    float* gb    = alloc((size_t)2048 * 256);
    float* mmb   = alloc((size_t)2048 * 256);
    float* xq    = alloc((size_t)2048 * 256);
    float* xnew  = alloc((size_t)2048 * 256);
    float* xout  = alloc((size_t)1024 * 256);
    float* dinv  = alloc(2048);
    float* ub    = alloc(2048);
    float* vb    = alloc(2048);
    float* aar   = alloc(2048);
    float* bbr   = alloc(2048);
    float* cfr   = alloc(2048);
    float* fit   = alloc(2048);
    float* fvals = alloc(2048);
    int*   perm  = (int*)alloc(2048);
    float* psum  = alloc(3 * 16 * FEAT);
    float* pmax  = alloc(3 * 16 * FEAT);
    unsigned* bm = (unsigned*)alloc(NNODES * NNODES / 32);
    int*   rowcnt = (int*)alloc(2048);
    int*   rowptr = (int*)alloc(2052);
    int*   csr_cols = (int*)alloc(80000);
    float* sval     = alloc(80000);

    const float* x     = (const float*)d_in[0];
    const int*   ei    = (const int*)d_in[1];
    const float* cW1   = (const float*)d_in[2];
    const float* cb1   = (const float*)d_in[3];
    const float* cW2   = (const float*)d_in[4];
    const float* cb2   = (const float*)d_in[5];
    const float* clinW = (const float*)d_in[6];
    const float* clinb = (const float*)d_in[7];
    const float* cattw = (const float*)d_in[8];
    const float* cattb = (const float*)d_in[9];
    const float* cle1W = (const float*)d_in[10];
    const float* cle1b = (const float*)d_in[11];
    const float* cle2W = (const float*)d_in[12];
    const float* cle3W = (const float*)d_in[13];
    const float* cle3b = (const float*)d_in[14];
    const float* cl1W  = (const float*)d_in[15];
    const float* cl1b  = (const float*)d_in[16];
    const float* cl2W  = (const float*)d_in[17];
    const float* cl2b  = (const float*)d_in[18];

    // ================= level 0: bitmask CSR + sparse path =================
    {
        int n = NNODES, k = n >> 1;
        fill_zero_k<<<512, 256, 0, stream>>>((float*)bm, n * n / 32);
        scatter_bit_k<<<(in_sizes[1] / 2 + 255) / 256, 256, 0, stream>>>(
            ei, bm, n, in_sizes[1] / 2);
        countbits_k<<<n, 64, 0, stream>>>(bm, rowcnt, n);
        csr_scan_k<<<1, 256, 0, stream>>>(rowcnt, rowptr, dinv, n);
        fillcsr_bits_k<<<n, 64, 0, stream>>>(bm, rowptr, csr_cols, n);

        gemm64_nn_k<<<dim3(FEAT / 64, n / 64), 256, 0, stream>>>(
            x, cW1, nullptr, xW, n, FEAT, 128);
        sparse_gcn_k<<<n, 256, 0, stream>>>(rowptr, csr_cols, dinv, xW, cb1,
                                            cattw, vb, gb);
        sparse_mmax_k<<<n, 256, 0, stream>>>(rowptr, csr_cols, gb, mmb);
        gemm64_nn_k<<<dim3(FEAT / 64, n / 64), 256, 0, stream>>>(
            mmb, clinW, clinb, xq, n, FEAT, FEAT);
        sparse_score_k<<<n, 256, 0, stream>>>(rowptr, csr_cols, xq, cattw, vb, cattb, sval);
        sparse_xnew_k<<<n, 256, 0, stream>>>(rowptr, csr_cols, sval, gb,
                                             cle1W, cle1b, cle2W, cle3W, cle3b,
                                             aar, bbr, cfr, xnew);
        sparse_fitness_k<<<n, 256, 0, stream>>>(rowptr, csr_cols, aar, bbr, cfr, fit);
        topk_k<<<1, 1024, 0, stream>>>(fit, n, k, perm, fvals);
        gather_x_k<<<k, 256, 0, stream>>>(xnew, perm, fvals, xout);
        readout_part_k<<<k / 64, 256, 0, stream>>>(xout, psum, pmax, k, 0);

        fill_zero_k<<<2048, 256, 0, stream>>>(Sp, n * k);
        sp_fill_k<<<k, 256, 0, stream>>>(rowptr, csr_cols, sval, perm, Sp, k);
        z_k<<<n, 256, 0, stream>>>(rowptr, csr_cols, Sp, Zb, k);
        ac_k<<<k, 256, 0, stream>>>(rowptr, csr_cols, sval, perm, Zb, A_b, dinv, k);
    }

    // ================= levels 1-2: dense split-K path (fused combs) =================
    const float* Acur = A_b;
    float* Anext = A_a;
    const float* hcur = xout;
    int n = 1024;
    for (int lvl = 1; lvl < 3; lvl++) {
        int k = n >> 1;
        int S  = 8;
        int Sw = (n == 1024) ? 4 : 8;
        int nMN = n * FEAT;
        int cgrid = nMN / 4 / 256;

        gemm64_nn_part_k<<<dim3(FEAT / 64, n / 64, Sw), 256, 0, stream>>>(
            hcur, cW2, pbuf, n, FEAT, FEAT, FEAT / Sw);
        comb_k<<<cgrid, 256, 0, stream>>>(pbuf, xW, nullptr, nMN, FEAT, Sw, 0);
        gcn64_part_k<<<dim3(FEAT / 64, n / 64, S), 256, 0, stream>>>(
            Acur, dinv, xW, pbuf, n, n / S);
        comb_relu_v_k<<<cgrid, 256, 0, stream>>>(pbuf, gb, cb2, dinv, cattw, vb, nMN, S);
        mmax64_part_k<<<dim3(FEAT / 64, n / 64, S), 256, 0, stream>>>(
            Acur, gb, pbuf, n, n / S);
        comb_k<<<cgrid, 256, 0, stream>>>(pbuf, mmb, nullptr, nMN, FEAT, S, 1);
        gemm64_nn_part_k<<<dim3(FEAT / 64, n / 64, Sw), 256, 0, stream>>>(
            mmb, clinW, pbuf, n, FEAT, FEAT, FEAT / Sw);
        comb_sum_u_k<<<cgrid, 256, 0, stream>>>(pbuf, xq, clinb, cattw, ub, nMN, Sw);
        score_k<<<n, 256, 0, stream>>>(Acur, ub, vb, cattb, Tm, n);
        gemm64_nn_part_k<<<dim3(FEAT / 64, n / 64, S), 256, 0, stream>>>(
            Tm, gb, pbuf, n, FEAT, n, n / S);
        comb_sum_abc_k<<<cgrid, 256, 0, stream>>>(pbuf, xnew, cle1W, cle1b, cle2W,
                                                  cle3W, cle3b, aar, bbr, cfr, nMN, S);
        fitness_k<<<n, 256, 0, stream>>>(Acur, aar, bbr, cfr, fit, n);
        topk_k<<<1, 1024, 0, stream>>>(fit, n, k, perm, fvals);
        gather_x_k<<<k, 256, 0, stream>>>(xnew, perm, fvals, xout);
        readout_part_k<<<k / 64, 256, 0, stream>>>(xout, psum, pmax, k, lvl * 16 * FEAT);
        if (lvl < 2) {
            gemm64_maskBp_part_k<<<dim3(n / 64, k / 64, 4), 256, 0, stream>>>(
                Tm, perm, Acur, pbuf, k, n, n, n / 4);
            comb_k<<<(k * n / 4) / 256, 256, 0, stream>>>(
                pbuf, Yb, nullptr, k * n, n, 4, 0);
            gemm64_ntp_part_k<<<dim3(k / 64, k / 64, 8), 256, 0, stream>>>(
                Yb, Tm, perm, pbuf, k, k, n, n / 8);
            comb_diag_deg_k<<<(k * k / 4) / 256, 256, 0, stream>>>(
                pbuf, Anext, dinv, k * k, k, 8);
        }
        const float* tswap = Acur;
        Acur = Anext;
        Anext = (float*)tswap;
        hcur = xout;
        n = k;
    }

    final_k<<<1, 256, 0, stream>>>(psum, pmax, cl1W, cl1b, cl2W, cl2b,
                                   (float*)d_out, out_size);
}